// Round 2
// baseline (144.220 us; speedup 1.0000x reference)
//
#include <hip/hip_runtime.h>
#include <math.h>

#define THREADS 256

// Exact online-softmax accumulate of one float4 chunk, deferred rescale:
// only pay the rescale exp when the chunk max beats the running max.
__device__ __forceinline__ void acc4(float4 v, float& m, float& s) {
    float vm = fmaxf(fmaxf(v.x, v.y), fmaxf(v.z, v.w));
    if (vm > m) { s *= __expf(m - vm); m = vm; }   // first time: s=0*exp(-inf)=0, m=vm
    s += __expf(v.x - m) + __expf(v.y - m) + __expf(v.z - m) + __expf(v.w - m);
}

__device__ __forceinline__ void acc1(float v, float& m, float& s) {
    if (v > m) { s *= __expf(m - v); m = v; }
    s += __expf(v - m);
}

// Combine two online-softmax partial states (m1,s1) <- (m1,s1) ⊕ (m2,s2)
__device__ __forceinline__ void combine_ms(float& m, float& s, float m2, float s2) {
    float nm = fmaxf(m, m2);
    if (nm == -INFINITY) { m = nm; s = 0.0f; return; }   // both empty: avoid inf-inf = NaN
    s = s * __expf(m - nm) + s2 * __expf(m2 - nm);
    m = nm;
}

__global__ __launch_bounds__(THREADS)
void ce_nll_kernel(const float* __restrict__ logits,
                   const int*   __restrict__ target,
                   float*       __restrict__ out,
                   int C) {
    const int n   = blockIdx.x;
    const int tid = threadIdx.x;
    const float* row = logits + (size_t)n * (size_t)C;

    // Row base is only 4B-aligned (C*4 = 201028 B, %16 != 0 for odd n).
    // Scalar lead-in to 16B alignment, float4 body, scalar tail.
    uintptr_t addr = (uintptr_t)row;
    int mis  = (int)((addr >> 2) & 3);
    int lead = (4 - mis) & 3;
    if (lead > C) lead = C;
    const int rem  = C - lead;
    const int nvec = rem >> 2;
    const int tail = rem & 3;

    float m0 = -INFINITY, s0 = 0.0f;
    float m1 = -INFINITY, s1 = 0.0f;
    float m2 = -INFINITY, s2 = 0.0f;
    float m3 = -INFINITY, s3 = 0.0f;

    if (tid < lead) { m0 = row[tid]; s0 = 1.0f; }

    const float4* vrow = (const float4*)(row + lead);

    // 4-deep unroll: 4 independent loads in flight, 4 independent online states.
    int i = tid;
    for (; i + 3 * THREADS < nvec; i += 4 * THREADS) {
        float4 a = vrow[i];
        float4 b = vrow[i +     THREADS];
        float4 c = vrow[i + 2 * THREADS];
        float4 d = vrow[i + 3 * THREADS];
        acc4(a, m0, s0);
        acc4(b, m1, s1);
        acc4(c, m2, s2);
        acc4(d, m3, s3);
    }
    for (; i < nvec; i += THREADS) acc4(vrow[i], m0, s0);

    if (tid < tail) acc1(row[lead + (nvec << 2) + tid], m1, s1);

    // merge the 4 per-thread states
    combine_ms(m0, s0, m1, s1);
    combine_ms(m2, s2, m3, s3);
    combine_ms(m0, s0, m2, s2);

    // wave-level butterfly reduce (64 lanes)
    #pragma unroll
    for (int off = 32; off > 0; off >>= 1) {
        float mm = __shfl_xor(m0, off, 64);
        float ss2 = __shfl_xor(s0, off, 64);
        combine_ms(m0, s0, mm, ss2);
    }

    // cross-wave reduce via LDS (4 waves)
    __shared__ float smem_m[THREADS / 64], smem_s[THREADS / 64];
    const int wid  = tid >> 6;
    const int lane = tid & 63;
    if (lane == 0) { smem_m[wid] = m0; smem_s[wid] = s0; }
    __syncthreads();

    if (tid == 0) {
        #pragma unroll
        for (int w = 1; w < THREADS / 64; ++w) combine_ms(m0, s0, smem_m[w], smem_s[w]);
        const int t  = target[n];
        const float lt = row[t];                 // L2-warm after the streaming pass
        out[n] = (m0 + __logf(s0)) - lt;         // nll = logsumexp - logit_target
    }
}

extern "C" void kernel_launch(void* const* d_in, const int* in_sizes, int n_in,
                              void* d_out, int out_size, void* d_ws, size_t ws_size,
                              hipStream_t stream) {
    const float* logits = (const float*)d_in[0];
    const int*   target = (const int*)d_in[1];
    float*       out    = (float*)d_out;

    const int N = out_size;                      // 4096 rows
    const int C = in_sizes[0] / N;               // 50257 classes

    ce_nll_kernel<<<N, THREADS, 0, stream>>>(logits, target, out, C);
}

// Round 3
// 131.553 us; speedup vs baseline: 1.0963x; 1.0963x over previous
//
#include <hip/hip_runtime.h>
#include <math.h>

#define THREADS 256

typedef float f32x4 __attribute__((ext_vector_type(4)));

// Exact online-softmax accumulate of one 4-float chunk, deferred rescale:
// only pay the rescale exp when the chunk max beats the running max.
__device__ __forceinline__ void acc4(f32x4 v, float& m, float& s) {
    float vm = fmaxf(fmaxf(v.x, v.y), fmaxf(v.z, v.w));
    if (vm > m) { s *= __expf(m - vm); m = vm; }   // first time: s=0*exp(-inf)=0, m=vm
    s += __expf(v.x - m) + __expf(v.y - m) + __expf(v.z - m) + __expf(v.w - m);
}

__device__ __forceinline__ void acc1(float v, float& m, float& s) {
    if (v > m) { s *= __expf(m - v); m = v; }
    s += __expf(v - m);
}

// Combine two online-softmax partial states (m1,s1) <- (m1,s1) ⊕ (m2,s2)
__device__ __forceinline__ void combine_ms(float& m, float& s, float m2, float s2) {
    float nm = fmaxf(m, m2);
    if (nm == -INFINITY) { m = nm; s = 0.0f; return; }   // both empty: avoid inf-inf = NaN
    s = s * __expf(m - nm) + s2 * __expf(m2 - nm);
    m = nm;
}

__global__ __launch_bounds__(THREADS)
void ce_nll_kernel(const float* __restrict__ logits,
                   const int*   __restrict__ target,
                   float*       __restrict__ out,
                   int C) {
    const int n   = blockIdx.x;
    const int tid = threadIdx.x;
    const float* row = logits + (size_t)n * (size_t)C;

    // Row base is only 4B-aligned (C*4 = 201028 B, %16 != 0 for odd n).
    // Scalar lead-in to 16B alignment, float4 body, scalar tail.
    uintptr_t addr = (uintptr_t)row;
    int mis  = (int)((addr >> 2) & 3);
    int lead = (4 - mis) & 3;
    if (lead > C) lead = C;
    const int rem  = C - lead;
    const int nvec = rem >> 2;
    const int tail = rem & 3;

    float m0 = -INFINITY, s0 = 0.0f;
    float m1 = -INFINITY, s1 = 0.0f;
    float m2 = -INFINITY, s2 = 0.0f;
    float m3 = -INFINITY, s3 = 0.0f;

    if (tid < lead) { m0 = row[tid]; s0 = 1.0f; }

    const f32x4* vrow = (const f32x4*)(row + lead);

    // 4-deep unroll, nontemporal loads: data is read exactly once — tell the
    // cache hierarchy not to retain the lines (global_load_dwordx4 ... nt).
    int i = tid;
    for (; i + 3 * THREADS < nvec; i += 4 * THREADS) {
        f32x4 a = __builtin_nontemporal_load(vrow + i);
        f32x4 b = __builtin_nontemporal_load(vrow + i +     THREADS);
        f32x4 c = __builtin_nontemporal_load(vrow + i + 2 * THREADS);
        f32x4 d = __builtin_nontemporal_load(vrow + i + 3 * THREADS);
        acc4(a, m0, s0);
        acc4(b, m1, s1);
        acc4(c, m2, s2);
        acc4(d, m3, s3);
    }
    for (; i < nvec; i += THREADS) acc4(__builtin_nontemporal_load(vrow + i), m0, s0);

    if (tid < tail) acc1(row[lead + (nvec << 2) + tid], m1, s1);

    // merge the 4 per-thread states
    combine_ms(m0, s0, m1, s1);
    combine_ms(m2, s2, m3, s3);
    combine_ms(m0, s0, m2, s2);

    // wave-level butterfly reduce (64 lanes)
    #pragma unroll
    for (int off = 32; off > 0; off >>= 1) {
        float mm  = __shfl_xor(m0, off, 64);
        float ss2 = __shfl_xor(s0, off, 64);
        combine_ms(m0, s0, mm, ss2);
    }

    // cross-wave reduce via LDS (4 waves)
    __shared__ float smem_m[THREADS / 64], smem_s[THREADS / 64];
    const int wid  = tid >> 6;
    const int lane = tid & 63;
    if (lane == 0) { smem_m[wid] = m0; smem_s[wid] = s0; }
    __syncthreads();

    if (tid == 0) {
        #pragma unroll
        for (int w = 1; w < THREADS / 64; ++w) combine_ms(m0, s0, smem_m[w], smem_s[w]);
        const int t  = target[n];
        const float lt = row[t];                 // single gather; fine if it misses
        out[n] = (m0 + __logf(s0)) - lt;         // nll = logsumexp - logit_target
    }
}

extern "C" void kernel_launch(void* const* d_in, const int* in_sizes, int n_in,
                              void* d_out, int out_size, void* d_ws, size_t ws_size,
                              hipStream_t stream) {
    const float* logits = (const float*)d_in[0];
    const int*   target = (const int*)d_in[1];
    float*       out    = (float*)d_out;

    const int N = out_size;                      // 4096 rows
    const int C = in_sizes[0] / N;               // 50257 classes

    ce_nll_kernel<<<N, THREADS, 0, stream>>>(logits, target, out, C);
}